// Round 7
// baseline (6890.078 us; speedup 1.0000x reference)
//
#include <hip/hip_runtime.h>
#include <hip/hip_bf16.h>
#include <stdint.h>

typedef unsigned short ushort_t;
typedef __attribute__((ext_vector_type(8))) short short8;
typedef __attribute__((ext_vector_type(4))) float f32x4;

// ---- helpers ----------------------------------------------------------------
__device__ __forceinline__ ushort_t f2b(float f) {  // fp32 -> bf16 (RNE)
  union { float f; uint32_t u; } c; c.f = f;
  return (ushort_t)((c.u + 0x7fffu + ((c.u >> 16) & 1u)) >> 16);
}
__device__ __forceinline__ float b2f(ushort_t b) {
  union { float f; uint32_t u; } c; c.u = ((uint32_t)b) << 16;
  return c.f;
}

// ---- naive f32 GEMM: C[M,N] = A[M,K] * B[K,N] + bias ------------------------
// B read in NATURAL [K][N] row-major layout (no transpose anywhere).
// MODE 0: scatter bf16 to q/k/v [B,H,T,D] (N=3072); MODE 1: *** f32 [M][N] ***
template <int MODE, bool AF32>
__global__ __launch_bounds__(256) void gemm_naive(
    const void* __restrict__ A_, const float* __restrict__ B,
    const float* __restrict__ bias,
    ushort_t* __restrict__ q_out, ushort_t* __restrict__ k_out,
    ushort_t* __restrict__ v_out, float* __restrict__ f_out,
    int M, int N, int K) {
  __shared__ float As[32][33];
  __shared__ float Bs[32][33];
  const int tid = threadIdx.x;  // 256 threads
  const int tx = tid & 15, ty = tid >> 4;
  const int row0 = blockIdx.y * 32, col0 = blockIdx.x * 32;
  float acc[2][2] = {{0.f, 0.f}, {0.f, 0.f}};

  for (int kk = 0; kk < K; kk += 32) {
    __syncthreads();
#pragma unroll
    for (int i = 0; i < 4; i++) {  // stage 32x32 A and B tiles
      const int idx = i * 256 + tid;  // [0,1024)
      const int r = idx >> 5, c = idx & 31;
      float av;
      if (AF32)
        av = ((const float*)A_)[(size_t)(row0 + r) * K + kk + c];
      else
        av = b2f(((const ushort_t*)A_)[(size_t)(row0 + r) * K + kk + c]);
      As[r][c] = av;
      Bs[r][c] = B[(size_t)(kk + r) * N + col0 + c];
    }
    __syncthreads();
#pragma unroll 8
    for (int k2 = 0; k2 < 32; k2++) {
      const float a0 = As[ty * 2][k2], a1 = As[ty * 2 + 1][k2];
      const float b0 = Bs[k2][tx * 2], b1 = Bs[k2][tx * 2 + 1];
      acc[0][0] += a0 * b0;
      acc[0][1] += a0 * b1;
      acc[1][0] += a1 * b0;
      acc[1][1] += a1 * b1;
    }
  }

#pragma unroll
  for (int i = 0; i < 2; i++) {
#pragma unroll
    for (int j = 0; j < 2; j++) {
      const int row = row0 + ty * 2 + i, col = col0 + tx * 2 + j;
      const float v = acc[i][j] + bias[col];
      if (MODE == 0) {
        // qkv[row][col]: col = which*1024 + h*64 + d; row = b*4096 + t
        const int which = col >> 10, h = (col >> 6) & 15, d = col & 63;
        const int bb = row >> 12, t = row & 4095;
        ushort_t* dst = which == 0 ? q_out : (which == 1 ? k_out : v_out);
        dst[(size_t)((bb * 16 + h) * 4096 + t) * 64 + d] = f2b(v);
      } else {
        f_out[(size_t)row * N + col] = v;  // *** f32 output (the probe) ***
      }
    }
  }
}

// ---- sparse attention, scalar verified-by-construction (UNCHANGED) ----------
#define SLP 68  // bf16 LDS row stride
__global__ __launch_bounds__(256) void sparse_attn_simple(
    const ushort_t* __restrict__ Qb, const ushort_t* __restrict__ Kb,
    const ushort_t* __restrict__ Vb, ushort_t* __restrict__ Y) {
  __shared__ __align__(16) ushort_t Qls[64 * SLP];
  __shared__ __align__(16) ushort_t Kls[64 * SLP];
  __shared__ __align__(16) ushort_t Vls[64 * SLP];
  __shared__ float Sls[64][65];
  const int tid = threadIdx.x;
  const int i = tid & 63, g = tid >> 6;
  const int qt = blockIdx.x, h = blockIdx.y, b = blockIdx.z;
  const int q0 = qt * 64;
  const size_t ho = (size_t)(b * 16 + h) * 4096 * 64;
  const ushort_t* Qp = Qb + ho;
  const ushort_t* Kp = Kb + ho;
  const ushort_t* Vp = Vb + ho;
  const float scale = 0.125f;

#pragma unroll
  for (int it = 0; it < 2; it++) {  // stage Q tile
    const int idx = it * 256 + tid;
    const int r = idx >> 3, c = (idx & 7) * 8;
    *(short8*)&Qls[r * SLP + c] = *(const short8*)&Qp[(size_t)(q0 + r) * 64 + c];
  }
  __syncthreads();

  float q[64];
#pragma unroll
  for (int d = 0; d < 64; d++) q[d] = b2f(Qls[i * SLP + d]);

  float o[16];
#pragma unroll
  for (int d = 0; d < 16; d++) o[d] = 0.f;
  float mrun = -1e30f, lrun = 0.f;
  const int iabs = q0 + i;

  for (int kt = 0; kt <= qt; kt++) {
    const int k0 = kt * 64, dq = q0 - k0;
    if (!(k0 == 0 || dq <= 256 || (dq & 127) == 0)) continue;  // block-uniform
    __syncthreads();  // prior-iteration Sls/Kls/Vls reads complete
#pragma unroll
    for (int it = 0; it < 2; it++) {  // stage K,V tiles [key][d]
      const int idx = it * 256 + tid;
      const int r = idx >> 3, c = (idx & 7) * 8;
      *(short8*)&Kls[r * SLP + c] =
          *(const short8*)&Kp[(size_t)(k0 + r) * 64 + c];
      *(short8*)&Vls[r * SLP + c] =
          *(const short8*)&Vp[(size_t)(k0 + r) * 64 + c];
    }
    __syncthreads();

    // scores: thread (i,g) computes s[i][j] for j in [16g,16g+16)
#pragma unroll
    for (int jj = 0; jj < 16; jj++) {
      const int j = g * 16 + jj;
      float s = 0.f;
#pragma unroll
      for (int d = 0; d < 64; d += 2) {
        const uint32_t u = *(const uint32_t*)&Kls[j * SLP + d];
        union { uint32_t u; float f; } lo, hi;
        lo.u = u << 16;
        hi.u = u & 0xffff0000u;
        s += q[d] * lo.f + q[d + 1] * hi.f;
      }
      Sls[i][j] = s;
    }
    __syncthreads();

    // masked online softmax (replicated across g-threads of row i)
    float mt = -1e30f;
#pragma unroll
    for (int j = 0; j < 64; j++) {
      const int jabs = k0 + j;
      const int dist = iabs - jabs;
      const bool ok =
          (dist >= 0) && ((dist < 256) || ((dist & 127) == 0) || (jabs < 16));
      const float v = ok ? Sls[i][j] * scale : -1e30f;
      mt = fmaxf(mt, v);
    }
    const float mnew = fmaxf(mrun, mt);
    const float alpha = __expf(mrun - mnew);
    float lt = 0.f;
    float e16[16];
#pragma unroll
    for (int j = 0; j < 64; j++) {
      const int jabs = k0 + j;
      const int dist = iabs - jabs;
      const bool ok =
          (dist >= 0) && ((dist < 256) || ((dist & 127) == 0) || (jabs < 16));
      const float v = ok ? Sls[i][j] * scale : -1e30f;
      const float e = __expf(v - mnew);
      lt += e;
      if ((j >> 4) == g) e16[j & 15] = e;
    }
    __syncthreads();  // all raw-score reads complete before overwrite
#pragma unroll
    for (int jj = 0; jj < 16; jj++) Sls[i][g * 16 + jj] = e16[jj];
    mrun = mnew;
    lrun = lrun * alpha + lt;
#pragma unroll
    for (int d = 0; d < 16; d++) o[d] *= alpha;
    __syncthreads();  // p complete before PV reads

    // PV: o[d] += p[key] * V[key][16g+d]
#pragma unroll
    for (int key = 0; key < 64; key++) {
      const float p = Sls[i][key];
#pragma unroll
      for (int d = 0; d < 16; d += 2) {
        const uint32_t u = *(const uint32_t*)&Vls[key * SLP + g * 16 + d];
        union { uint32_t u; float f; } lo, hi;
        lo.u = u << 16;
        hi.u = u & 0xffff0000u;
        o[d] += p * lo.f;
        o[d + 1] += p * hi.f;
      }
    }
  }

#pragma unroll
  for (int d = 0; d < 16; d++) {
    Y[(size_t)(b * 4096 + q0 + i) * 1024 + h * 64 + g * 16 + d] =
        f2b(o[d] / lrun);
  }
}

// ---- launch -----------------------------------------------------------------
static const void* by_size(void* const* d_in, const int* in_sizes, int n_in,
                           int want, int fallback_idx) {
  for (int i = 0; i < n_in; i++)
    if (in_sizes[i] == want) return d_in[i];
  return d_in[fallback_idx];
}

extern "C" void kernel_launch(void* const* d_in, const int* in_sizes, int n_in,
                              void* d_out, int out_size, void* d_ws,
                              size_t ws_size, hipStream_t stream) {
  const float* x      = (const float*)by_size(d_in, in_sizes, n_in, 8388608, 0);
  const float* w_qkv  = (const float*)by_size(d_in, in_sizes, n_in, 3145728, 1);
  const float* b_qkv  = (const float*)by_size(d_in, in_sizes, n_in, 3072, 2);
  const float* w_proj = (const float*)by_size(d_in, in_sizes, n_in, 1048576, 3);
  const float* b_proj = (const float*)by_size(d_in, in_sizes, n_in, 1024, 4);
  float* out = (float*)d_out;                   // *** probe: f32 output ***
  char* ws = (char*)d_ws;
  ushort_t* qb     = (ushort_t*)(ws + 8388608);   // 16.8 MB bf16 [B,H,T,D]
  ushort_t* kb     = (ushort_t*)(ws + 25165824);
  ushort_t* vb     = (ushort_t*)(ws + 41943040);
  ushort_t* yb     = (ushort_t*)(ws + 58720256);  // 16.8 MB bf16 [8192,1024]

  if (ws_size < 75497472) return;  // proven satisfied (output was nonzero)

  // QKV: x[8192,1024] @ w_qkv[1024,3072] (natural layout) -> scatter q/k/v
  gemm_naive<0, true><<<dim3(96, 256), 256, 0, stream>>>(
      x, w_qkv, b_qkv, qb, kb, vb, nullptr, 8192, 3072, 1024);
  sparse_attn_simple<<<dim3(64, 16, 2), 256, 0, stream>>>(qb, kb, vb, yb);
  // proj: yb[8192,1024] @ w_proj[1024,1024] (natural layout) -> out (f32)
  gemm_naive<1, false><<<dim3(32, 256), 256, 0, stream>>>(
      yb, w_proj, b_proj, nullptr, nullptr, nullptr, out, 8192, 1024, 1024);
}

// Round 8
// 464.343 us; speedup vs baseline: 14.8383x; 14.8383x over previous
//
#include <hip/hip_runtime.h>
#include <hip/hip_bf16.h>
#include <stdint.h>

typedef unsigned short ushort_t;
typedef __attribute__((ext_vector_type(8))) __bf16 bf16x8;
typedef __attribute__((ext_vector_type(8))) short short8;
typedef __attribute__((ext_vector_type(4))) float f32x4;

// ---- helpers ----------------------------------------------------------------
__device__ __forceinline__ ushort_t f2b(float f) {  // fp32 -> bf16 (RNE)
  union { float f; uint32_t u; } c; c.f = f;
  return (ushort_t)((c.u + 0x7fffu + ((c.u >> 16) & 1u)) >> 16);
}

// ---- transpose f32 [K][N] -> bf16 [N][K] ------------------------------------
__global__ __launch_bounds__(256) void transpose_f2b(
    const float* __restrict__ in, ushort_t* __restrict__ out, int K, int N) {
  __shared__ __align__(16) ushort_t tile[64][72];
  const int k0 = blockIdx.x * 64, n0 = blockIdx.y * 64;
  const int tid = threadIdx.x;
#pragma unroll
  for (int i = 0; i < 4; i++) {
    const int idx = i * 256 + tid;           // [0,1024)
    const int r = idx >> 4, c = (idx & 15) * 4;
    const f32x4 a = *(const f32x4*)&in[(size_t)(k0 + r) * N + n0 + c];
#pragma unroll
    for (int j = 0; j < 4; j++) tile[r][c + j] = f2b(a[j]);
  }
  __syncthreads();
#pragma unroll
  for (int i = 0; i < 16; i++) {
    const int idx = i * 256 + tid;
    const int r = idx >> 6, c = idx & 63;
    out[(size_t)(n0 + r) * K + k0 + c] = tile[c][r];
  }
}

// ---- GEMM: C[M,N] = A[M,K] * Bt[N,K]^T + bias -------------------------------
// A is f32 (AF32) or bf16; Bt is bf16 [N][K]; bias f32.
// MODE 0: scatter bf16 into q/k/v [B,H,T,D].  MODE 1: f32 row-major out.
template <int MODE, bool AF32>
__global__ __launch_bounds__(256) void gemm_bt(
    const void* __restrict__ A_, const ushort_t* __restrict__ Bt,
    const float* __restrict__ bias,
    ushort_t* __restrict__ q_out, ushort_t* __restrict__ k_out,
    ushort_t* __restrict__ v_out, float* __restrict__ f_out,
    int M, int N, int K) {
  __shared__ __align__(16) ushort_t Als[128 * 64];
  __shared__ __align__(16) ushort_t Bls[128 * 64];
  const int tid = threadIdx.x;
  const int wave = tid >> 6, lane = tid & 63;
  const int quad = lane >> 4, l15 = lane & 15;
  const int wr = wave >> 1, wc = wave & 1;
  const int rowBase = blockIdx.y * 128;
  const int colBase = blockIdx.x * 128;
  const f32x4 fzero = {0.f, 0.f, 0.f, 0.f};

  f32x4 acc[4][4];
#pragma unroll
  for (int mi = 0; mi < 4; mi++)
#pragma unroll
    for (int ni = 0; ni < 4; ni++) acc[mi][ni] = fzero;

  const int srow = tid >> 3;       // 0..31
  const int scol = (tid & 7) * 8;  // 0,8,...,56 (elements)

  for (int kk = 0; kk < K; kk += 64) {
    __syncthreads();
#pragma unroll
    for (int s = 0; s < 4; s++) {
      const int r = s * 32 + srow;
      if (AF32) {
        const float* Af = (const float*)A_;
        const f32x4 u0 =
            *(const f32x4*)&Af[(size_t)(rowBase + r) * K + kk + scol];
        const f32x4 u1 =
            *(const f32x4*)&Af[(size_t)(rowBase + r) * K + kk + scol + 4];
        short8 t;
#pragma unroll
        for (int j = 0; j < 4; j++) t[j] = (short)f2b(u0[j]);
#pragma unroll
        for (int j = 0; j < 4; j++) t[4 + j] = (short)f2b(u1[j]);
        *(short8*)&Als[r * 64 + scol] = t;
      } else {
        const ushort_t* Ab = (const ushort_t*)A_;
        *(short8*)&Als[r * 64 + scol] =
            *(const short8*)&Ab[(size_t)(rowBase + r) * K + kk + scol];
      }
      *(short8*)&Bls[r * 64 + scol] =
          *(const short8*)&Bt[(size_t)(colBase + r) * K + kk + scol];
    }
    __syncthreads();
#pragma unroll
    for (int ks = 0; ks < 2; ks++) {
      const int ko = ks * 32 + quad * 8;
      bf16x8 af[4], bfr[4];
#pragma unroll
      for (int mi = 0; mi < 4; mi++)
        af[mi] = *(const bf16x8*)&Als[(wr * 64 + mi * 16 + l15) * 64 + ko];
#pragma unroll
      for (int ni = 0; ni < 4; ni++)
        bfr[ni] = *(const bf16x8*)&Bls[(wc * 64 + ni * 16 + l15) * 64 + ko];
#pragma unroll
      for (int mi = 0; mi < 4; mi++)
#pragma unroll
        for (int ni = 0; ni < 4; ni++)
          acc[mi][ni] = __builtin_amdgcn_mfma_f32_16x16x32_bf16(
              af[mi], bfr[ni], acc[mi][ni], 0, 0, 0);
    }
  }

  if (MODE == 0) {
    const int which = colBase >> 10;  // uniform per block (0/1/2 = q/k/v)
    ushort_t* dst = which == 0 ? q_out : (which == 1 ? k_out : v_out);
    const int h = ((colBase & 1023) >> 6) + wc;
#pragma unroll
    for (int mi = 0; mi < 4; mi++) {
#pragma unroll
      for (int ni = 0; ni < 4; ni++) {
        const int d = ni * 16 + l15;
        const float bv = bias[colBase + wc * 64 + d];
#pragma unroll
        for (int r = 0; r < 4; r++) {
          const int row = rowBase + wr * 64 + mi * 16 + quad * 4 + r;
          const int bidx = row >> 12, t = row & 4095;
          dst[(size_t)((bidx * 16 + h) * 4096 + t) * 64 + d] =
              f2b(acc[mi][ni][r] + bv);
        }
      }
    }
  } else {
#pragma unroll
    for (int mi = 0; mi < 4; mi++) {
#pragma unroll
      for (int ni = 0; ni < 4; ni++) {
        const int col = colBase + wc * 64 + ni * 16 + l15;
        const float bv = bias[col];
#pragma unroll
        for (int r = 0; r < 4; r++) {
          const int row = rowBase + wr * 64 + mi * 16 + quad * 4 + r;
          f_out[(size_t)row * N + col] = acc[mi][ni][r] + bv;  // f32 out
        }
      }
    }
  }
}

// ---- sparse flash attention (MFMA) ------------------------------------------
// grid (T/64, NH, B); block 256 (4 waves; wave w owns q rows [16w,16w+16))
#define LP 72  // LDS row stride (pad: 16B-aligned rows)
__global__ __launch_bounds__(256) void sparse_attn(
    const ushort_t* __restrict__ Qb, const ushort_t* __restrict__ Kb,
    const ushort_t* __restrict__ Vb, ushort_t* __restrict__ Y) {
  __shared__ __align__(16) ushort_t Qls[64 * LP];
  __shared__ __align__(16) ushort_t Kls[64 * LP];
  __shared__ __align__(16) ushort_t Vtls[64 * LP];   // [d][key]
  __shared__ __align__(16) ushort_t Pls[4 * 16 * LP];
  const int tid = threadIdx.x;
  const int wave = tid >> 6, lane = tid & 63;
  const int quad = lane >> 4, l15 = lane & 15;
  const int qt = blockIdx.x, h = blockIdx.y, b = blockIdx.z;
  const int q0 = qt * 64;
  const size_t headoff = (size_t)(b * 16 + h) * 4096 * 64;
  const ushort_t* Qp = Qb + headoff;
  const ushort_t* Kp = Kb + headoff;
  const ushort_t* Vp = Vb + headoff;
  const f32x4 fzero = {0.f, 0.f, 0.f, 0.f};

#pragma unroll
  for (int i = 0; i < 2; i++) {
    const int idx = i * 256 + tid;
    const int r = idx >> 3, c = (idx & 7) * 8;
    *(short8*)&Qls[r * LP + c] = *(const short8*)&Qp[(size_t)(q0 + r) * 64 + c];
  }
  __syncthreads();
  bf16x8 qf[2];
#pragma unroll
  for (int ks = 0; ks < 2; ks++)
    qf[ks] = *(const bf16x8*)&Qls[(wave * 16 + l15) * LP + ks * 32 + quad * 8];

  f32x4 o[4];
#pragma unroll
  for (int dt = 0; dt < 4; dt++) o[dt] = fzero;
  float mrun[4], lsum[4];
#pragma unroll
  for (int r = 0; r < 4; r++) { mrun[r] = -1e30f; lsum[r] = 0.f; }
  ushort_t* Pw = &Pls[wave * 16 * LP];
  const float scale = 0.125f;

  for (int kt = 0; kt <= qt; kt++) {  // kt=0 first: every row gets finite max
    const int k0 = kt * 64;
    const int dq = q0 - k0;
    if (!(k0 == 0 || dq <= 256 || (dq & 127) == 0)) continue;  // block-uniform
    __syncthreads();
#pragma unroll
    for (int i = 0; i < 2; i++) {  // stage K [key][d]
      const int idx = i * 256 + tid;
      const int r = idx >> 3, c = (idx & 7) * 8;
      *(short8*)&Kls[r * LP + c] =
          *(const short8*)&Kp[(size_t)(k0 + r) * 64 + c];
    }
#pragma unroll
    for (int i = 0; i < 2; i++) {  // stage V transposed -> [d][key]
      const int idx = i * 256 + tid;
      const int key = idx & 63, dblk = (idx >> 6) * 8;
      short8 vv = *(const short8*)&Vp[(size_t)(k0 + key) * 64 + dblk];
#pragma unroll
      for (int m = 0; m < 8; m++) Vtls[(dblk + m) * LP + key] = (ushort_t)vv[m];
    }
    __syncthreads();

    f32x4 sacc[4];  // S = Q K^T ; C-layout: col(key)=l15, row(q)=quad*4+reg
#pragma unroll
    for (int ni = 0; ni < 4; ni++) sacc[ni] = fzero;
#pragma unroll
    for (int ks = 0; ks < 2; ks++) {
      const int ko = ks * 32 + quad * 8;
#pragma unroll
      for (int ni = 0; ni < 4; ni++) {
        bf16x8 kf = *(const bf16x8*)&Kls[(ni * 16 + l15) * LP + ko];
        sacc[ni] =
            __builtin_amdgcn_mfma_f32_16x16x32_bf16(qf[ks], kf, sacc[ni], 0, 0, 0);
      }
    }

    float p[4][4];
    const int i0 = q0 + wave * 16 + quad * 4;
#pragma unroll
    for (int ni = 0; ni < 4; ni++) {
      const int j = k0 + ni * 16 + l15;
#pragma unroll
      for (int r = 0; r < 4; r++) {
        const int dist = i0 + r - j;
        const bool ok =
            (dist >= 0) && ((dist < 256) || ((dist & 127) == 0) || (j < 16));
        p[ni][r] = ok ? sacc[ni][r] * scale : -1e30f;
      }
    }

    float alpha[4];
#pragma unroll
    for (int r = 0; r < 4; r++) {
      float m = fmaxf(fmaxf(p[0][r], p[1][r]), fmaxf(p[2][r], p[3][r]));
      m = fmaxf(m, __shfl_xor(m, 1));
      m = fmaxf(m, __shfl_xor(m, 2));
      m = fmaxf(m, __shfl_xor(m, 4));
      m = fmaxf(m, __shfl_xor(m, 8));
      const float mnew = fmaxf(mrun[r], m);
      alpha[r] = __expf(mrun[r] - mnew);
      mrun[r] = mnew;
      float rs = 0.f;
#pragma unroll
      for (int ni = 0; ni < 4; ni++) {
        const float e = __expf(p[ni][r] - mnew);
        p[ni][r] = e;
        rs += e;
      }
      rs += __shfl_xor(rs, 1);
      rs += __shfl_xor(rs, 2);
      rs += __shfl_xor(rs, 4);
      rs += __shfl_xor(rs, 8);
      lsum[r] = lsum[r] * alpha[r] + rs;
    }
#pragma unroll
    for (int dt = 0; dt < 4; dt++)
#pragma unroll
      for (int r = 0; r < 4; r++) o[dt][r] *= alpha[r];

    // P: C-layout -> A-layout via LDS round trip.
#pragma unroll
    for (int ni = 0; ni < 4; ni++)
#pragma unroll
      for (int r = 0; r < 4; r++)
        Pw[(quad * 4 + r) * LP + ni * 16 + l15] = f2b(p[ni][r]);
    __syncthreads();

#pragma unroll
    for (int ks = 0; ks < 2; ks++) {
      const int ko = ks * 32 + quad * 8;
      bf16x8 pf = *(const bf16x8*)&Pw[l15 * LP + ko];
#pragma unroll
      for (int dt = 0; dt < 4; dt++) {
        bf16x8 vf = *(const bf16x8*)&Vtls[(dt * 16 + l15) * LP + ko];
        o[dt] = __builtin_amdgcn_mfma_f32_16x16x32_bf16(pf, vf, o[dt], 0, 0, 0);
      }
    }
  }

#pragma unroll
  for (int dt = 0; dt < 4; dt++) {
#pragma unroll
    for (int r = 0; r < 4; r++) {
      const int t = q0 + wave * 16 + quad * 4 + r;
      const int c = h * 64 + dt * 16 + l15;
      Y[(size_t)(b * 4096 + t) * 1024 + c] = f2b(o[dt][r] / lsum[r]);
    }
  }
}

// ---- launch -----------------------------------------------------------------
static const void* by_size(void* const* d_in, const int* in_sizes, int n_in,
                           int want, int fallback_idx) {
  for (int i = 0; i < n_in; i++)
    if (in_sizes[i] == want) return d_in[i];
  return d_in[fallback_idx];
}

extern "C" void kernel_launch(void* const* d_in, const int* in_sizes, int n_in,
                              void* d_out, int out_size, void* d_ws,
                              size_t ws_size, hipStream_t stream) {
  const float* x      = (const float*)by_size(d_in, in_sizes, n_in, 8388608, 0);
  const float* w_qkv  = (const float*)by_size(d_in, in_sizes, n_in, 3145728, 1);
  const float* b_qkv  = (const float*)by_size(d_in, in_sizes, n_in, 3072, 2);
  const float* w_proj = (const float*)by_size(d_in, in_sizes, n_in, 1048576, 3);
  const float* b_proj = (const float*)by_size(d_in, in_sizes, n_in, 1024, 4);
  float* out = (float*)d_out;                     // [2,4096,1024] f32 (proven)
  char* ws = (char*)d_ws;
  ushort_t* wqkvT  = (ushort_t*)(ws);             //  6.3 MB bf16 [3072,1024]
  ushort_t* wprojT = (ushort_t*)(ws + 6291456);   //  2.1 MB bf16 [1024,1024]
  ushort_t* qb     = (ushort_t*)(ws + 8388608);   // 16.8 MB bf16 [B,H,T,D]
  ushort_t* kb     = (ushort_t*)(ws + 25165824);
  ushort_t* vb     = (ushort_t*)(ws + 41943040);
  ushort_t* yb     = (ushort_t*)(ws + 58720256);  // 16.8 MB bf16 [8192,1024]

  if (ws_size < 75497472) return;  // proven satisfied

  transpose_f2b<<<dim3(16, 48), 256, 0, stream>>>(w_qkv, wqkvT, 1024, 3072);
  transpose_f2b<<<dim3(16, 16), 256, 0, stream>>>(w_proj, wprojT, 1024, 1024);
  gemm_bt<0, true><<<dim3(24, 64), 256, 0, stream>>>(
      x, wqkvT, b_qkv, qb, kb, vb, nullptr, 8192, 3072, 1024);
  sparse_attn<<<dim3(64, 16, 2), 256, 0, stream>>>(qb, kb, vb, yb);
  gemm_bt<1, false><<<dim3(8, 64), 256, 0, stream>>>(
      yb, wprojT, b_proj, nullptr, nullptr, nullptr, out, 8192, 1024, 1024);
}

// Round 9
// 384.180 us; speedup vs baseline: 17.9345x; 1.2087x over previous
//
#include <hip/hip_runtime.h>
#include <hip/hip_bf16.h>
#include <stdint.h>

typedef unsigned short ushort_t;
typedef __attribute__((ext_vector_type(8))) __bf16 bf16x8;
typedef __attribute__((ext_vector_type(8))) short short8;
typedef __attribute__((ext_vector_type(4))) float f32x4;
typedef __attribute__((ext_vector_type(4))) unsigned int uint4v;

// ---- helpers ----------------------------------------------------------------
__device__ __forceinline__ ushort_t f2b(float f) {  // fp32 -> bf16 (RNE)
  union { float f; uint32_t u; } c; c.f = f;
  return (ushort_t)((c.u + 0x7fffu + ((c.u >> 16) & 1u)) >> 16);
}
__device__ __forceinline__ float b2f(ushort_t b) {
  union { float f; uint32_t u; } c; c.u = ((uint32_t)b) << 16;
  return c.f;
}
__device__ __forceinline__ float dot2bf(uint32_t qu, uint32_t ku, float acc) {
  union { uint32_t u; float f; } a, b, c, d;
  a.u = qu << 16; b.u = qu & 0xffff0000u;
  c.u = ku << 16; d.u = ku & 0xffff0000u;
  acc = fmaf(a.f, c.f, acc);
  return fmaf(b.f, d.f, acc);
}

// ---- elementwise f32 -> bf16 ------------------------------------------------
__global__ __launch_bounds__(256) void f32_to_b16(
    const float* __restrict__ in, ushort_t* __restrict__ out) {
  const int i = (blockIdx.x * 256 + threadIdx.x) * 8;
  const f32x4 a = *(const f32x4*)&in[i];
  const f32x4 b = *(const f32x4*)&in[i + 4];
  short8 t;
#pragma unroll
  for (int j = 0; j < 4; j++) { t[j] = (short)f2b(a[j]); t[4 + j] = (short)f2b(b[j]); }
  *(short8*)&out[i] = t;
}

// ---- transpose f32 [K][N] -> bf16 [N][K] ------------------------------------
__global__ __launch_bounds__(256) void transpose_f2b(
    const float* __restrict__ in, ushort_t* __restrict__ out, int K, int N) {
  __shared__ __align__(16) ushort_t tile[64][72];
  const int k0 = blockIdx.x * 64, n0 = blockIdx.y * 64;
  const int tid = threadIdx.x;
#pragma unroll
  for (int i = 0; i < 4; i++) {
    const int idx = i * 256 + tid;
    const int r = idx >> 4, c = (idx & 15) * 4;
    const f32x4 a = *(const f32x4*)&in[(size_t)(k0 + r) * N + n0 + c];
#pragma unroll
    for (int j = 0; j < 4; j++) tile[r][c + j] = f2b(a[j]);
  }
  __syncthreads();
#pragma unroll
  for (int i = 0; i < 16; i++) {
    const int idx = i * 256 + tid;
    const int r = idx >> 6, c = idx & 63;
    out[(size_t)(n0 + r) * K + k0 + c] = tile[c][r];
  }
}

// ---- GEMM: C[M,N] = A[M,K](bf16) * Bt[N,K]^T(bf16) + bias -------------------
// MODE 0: scatter bf16 into q/k/v [B,H,T,D].  MODE 1: f32 row-major out.
template <int MODE>
__global__ __launch_bounds__(256) void gemm_bt(
    const ushort_t* __restrict__ A, const ushort_t* __restrict__ Bt,
    const float* __restrict__ bias,
    ushort_t* __restrict__ q_out, ushort_t* __restrict__ k_out,
    ushort_t* __restrict__ v_out, float* __restrict__ f_out,
    int M, int N, int K) {
  __shared__ __align__(16) ushort_t Als[128 * 64];
  __shared__ __align__(16) ushort_t Bls[128 * 64];
  const int tid = threadIdx.x;
  const int wave = tid >> 6, lane = tid & 63;
  const int quad = lane >> 4, l15 = lane & 15;
  const int wr = wave >> 1, wc = wave & 1;
  const int rowBase = blockIdx.y * 128;
  const int colBase = blockIdx.x * 128;
  const f32x4 fzero = {0.f, 0.f, 0.f, 0.f};

  f32x4 acc[4][4];
#pragma unroll
  for (int mi = 0; mi < 4; mi++)
#pragma unroll
    for (int ni = 0; ni < 4; ni++) acc[mi][ni] = fzero;

  const int srow = tid >> 3;       // 0..31
  const int scol = (tid & 7) * 8;  // 0,8,...,56 (elements)

  for (int kk = 0; kk < K; kk += 64) {
    __syncthreads();
#pragma unroll
    for (int s = 0; s < 4; s++) {
      const int r = s * 32 + srow;
      *(short8*)&Als[r * 64 + scol] =
          *(const short8*)&A[(size_t)(rowBase + r) * K + kk + scol];
      *(short8*)&Bls[r * 64 + scol] =
          *(const short8*)&Bt[(size_t)(colBase + r) * K + kk + scol];
    }
    __syncthreads();
#pragma unroll
    for (int ks = 0; ks < 2; ks++) {
      const int ko = ks * 32 + quad * 8;
      bf16x8 af[4], bfr[4];
#pragma unroll
      for (int mi = 0; mi < 4; mi++)
        af[mi] = *(const bf16x8*)&Als[(wr * 64 + mi * 16 + l15) * 64 + ko];
#pragma unroll
      for (int ni = 0; ni < 4; ni++)
        bfr[ni] = *(const bf16x8*)&Bls[(wc * 64 + ni * 16 + l15) * 64 + ko];
#pragma unroll
      for (int mi = 0; mi < 4; mi++)
#pragma unroll
        for (int ni = 0; ni < 4; ni++)
          acc[mi][ni] = __builtin_amdgcn_mfma_f32_16x16x32_bf16(
              af[mi], bfr[ni], acc[mi][ni], 0, 0, 0);
    }
  }

  if (MODE == 0) {
    const int which = colBase >> 10;
    ushort_t* dst = which == 0 ? q_out : (which == 1 ? k_out : v_out);
    const int h = ((colBase & 1023) >> 6) + wc;
#pragma unroll
    for (int mi = 0; mi < 4; mi++) {
#pragma unroll
      for (int ni = 0; ni < 4; ni++) {
        const int d = ni * 16 + l15;
        const float bv = bias[colBase + wc * 64 + d];
#pragma unroll
        for (int r = 0; r < 4; r++) {
          const int row = rowBase + wr * 64 + mi * 16 + quad * 4 + r;
          const int bidx = row >> 12, t = row & 4095;
          dst[(size_t)((bidx * 16 + h) * 4096 + t) * 64 + d] =
              f2b(acc[mi][ni][r] + bv);
        }
      }
    }
  } else {
#pragma unroll
    for (int mi = 0; mi < 4; mi++) {
#pragma unroll
      for (int ni = 0; ni < 4; ni++) {
        const int col = colBase + wc * 64 + ni * 16 + l15;
        const float bv = bias[col];
#pragma unroll
        for (int r = 0; r < 4; r++) {
          const int row = rowBase + wr * 64 + mi * 16 + quad * 4 + r;
          f_out[(size_t)row * N + col] = acc[mi][ni][r] + bv;
        }
      }
    }
  }
}

// ---- sparse flash attention v2 ----------------------------------------------
// Exact partition for qt>=6: tile0(full mask) + window[qt-4..qt] + diagonal
// strided levels (s>=3, k0s>=64). qt<6: all tiles, full mask.
#define LP 72
__global__ __launch_bounds__(256) void sparse_attn(
    const ushort_t* __restrict__ Qb, const ushort_t* __restrict__ Kb,
    const ushort_t* __restrict__ Vb, ushort_t* __restrict__ Y) {
  __shared__ __align__(16) ushort_t Qls[64 * LP];
  __shared__ __align__(16) ushort_t Kls[64 * LP];
  __shared__ __align__(16) ushort_t Vtls[64 * LP];  // dense: [d][key]; strided: [key][d]
  __shared__ __align__(16) ushort_t Pls[4 * 16 * LP];
  const int tid = threadIdx.x;
  const int wave = tid >> 6, lane = tid & 63;
  const int quad = lane >> 4, l15 = lane & 15;
  const int qt = (int)gridDim.x - 1 - (int)blockIdx.x;  // heavy blocks first
  const int h = blockIdx.y, b = blockIdx.z;
  const int q0 = qt * 64;
  const size_t headoff = (size_t)(b * 16 + h) * 4096 * 64;
  const ushort_t* Qp = Qb + headoff;
  const ushort_t* Kp = Kb + headoff;
  const ushort_t* Vp = Vb + headoff;
  const f32x4 fzero = {0.f, 0.f, 0.f, 0.f};
  const float scale = 0.125f;

#pragma unroll
  for (int i = 0; i < 2; i++) {  // stage Q (kept resident all phases)
    const int idx = i * 256 + tid;
    const int r = idx >> 3, c = (idx & 7) * 8;
    *(short8*)&Qls[r * LP + c] = *(const short8*)&Qp[(size_t)(q0 + r) * 64 + c];
  }
  __syncthreads();
  bf16x8 qf[2];
#pragma unroll
  for (int ks = 0; ks < 2; ks++)
    qf[ks] = *(const bf16x8*)&Qls[(wave * 16 + l15) * LP + ks * 32 + quad * 8];

  f32x4 o[4];
#pragma unroll
  for (int dt = 0; dt < 4; dt++) o[dt] = fzero;
  float mrun[4], lsum[4];
#pragma unroll
  for (int r = 0; r < 4; r++) { mrun[r] = -1e30f; lsum[r] = 0.f; }
  ushort_t* Pw = &Pls[wave * 16 * LP];

  // mode: 0=no mask, 1=causal only, 2=dist<256||dist%128==0, 3=full
  auto dense_tile = [&](int k0, int mode) {
    __syncthreads();
#pragma unroll
    for (int i = 0; i < 2; i++) {  // K [key][d]
      const int idx = i * 256 + tid;
      const int r = idx >> 3, c = (idx & 7) * 8;
      *(short8*)&Kls[r * LP + c] = *(const short8*)&Kp[(size_t)(k0 + r) * 64 + c];
    }
#pragma unroll
    for (int i = 0; i < 2; i++) {  // V transposed [d][key]
      const int idx = i * 256 + tid;
      const int key = idx & 63, dblk = (idx >> 6) * 8;
      short8 vv = *(const short8*)&Vp[(size_t)(k0 + key) * 64 + dblk];
#pragma unroll
      for (int m = 0; m < 8; m++) Vtls[(dblk + m) * LP + key] = (ushort_t)vv[m];
    }
    __syncthreads();

    f32x4 sacc[4];
#pragma unroll
    for (int ni = 0; ni < 4; ni++) sacc[ni] = fzero;
#pragma unroll
    for (int ks = 0; ks < 2; ks++) {
      const int ko = ks * 32 + quad * 8;
#pragma unroll
      for (int ni = 0; ni < 4; ni++) {
        bf16x8 kf = *(const bf16x8*)&Kls[(ni * 16 + l15) * LP + ko];
        sacc[ni] = __builtin_amdgcn_mfma_f32_16x16x32_bf16(qf[ks], kf, sacc[ni], 0, 0, 0);
      }
    }

    float p[4][4];
    const int i0 = q0 + wave * 16 + quad * 4;
    if (mode == 0) {
#pragma unroll
      for (int ni = 0; ni < 4; ni++)
#pragma unroll
        for (int r = 0; r < 4; r++) p[ni][r] = sacc[ni][r] * scale;
    } else {
#pragma unroll
      for (int ni = 0; ni < 4; ni++) {
        const int j = k0 + ni * 16 + l15;
#pragma unroll
        for (int r = 0; r < 4; r++) {
          const int dist = i0 + r - j;
          bool ok;
          if (mode == 1)      ok = dist >= 0;
          else if (mode == 2) ok = (dist < 256) || ((dist & 127) == 0);
          else                ok = (dist >= 0) &&
                                   ((dist < 256) || ((dist & 127) == 0) || (j < 16));
          p[ni][r] = ok ? sacc[ni][r] * scale : -1e30f;
        }
      }
    }

    float alpha[4];
#pragma unroll
    for (int r = 0; r < 4; r++) {
      float m = fmaxf(fmaxf(p[0][r], p[1][r]), fmaxf(p[2][r], p[3][r]));
      m = fmaxf(m, __shfl_xor(m, 1));
      m = fmaxf(m, __shfl_xor(m, 2));
      m = fmaxf(m, __shfl_xor(m, 4));
      m = fmaxf(m, __shfl_xor(m, 8));
      const float mnew = fmaxf(mrun[r], m);
      alpha[r] = __expf(mrun[r] - mnew);
      mrun[r] = mnew;
      float rs = 0.f;
#pragma unroll
      for (int ni = 0; ni < 4; ni++) {
        const float e = __expf(p[ni][r] - mnew);
        p[ni][r] = e;
        rs += e;
      }
      rs += __shfl_xor(rs, 1);
      rs += __shfl_xor(rs, 2);
      rs += __shfl_xor(rs, 4);
      rs += __shfl_xor(rs, 8);
      lsum[r] = lsum[r] * alpha[r] + rs;
    }
#pragma unroll
    for (int dt = 0; dt < 4; dt++)
#pragma unroll
      for (int r = 0; r < 4; r++) o[dt][r] *= alpha[r];

#pragma unroll
    for (int ni = 0; ni < 4; ni++)
#pragma unroll
      for (int r = 0; r < 4; r++)
        Pw[(quad * 4 + r) * LP + ni * 16 + l15] = f2b(p[ni][r]);
    __syncthreads();

#pragma unroll
    for (int ks = 0; ks < 2; ks++) {
      const int ko = ks * 32 + quad * 8;
      bf16x8 pf = *(const bf16x8*)&Pw[l15 * LP + ko];
#pragma unroll
      for (int dt = 0; dt < 4; dt++) {
        bf16x8 vf = *(const bf16x8*)&Vtls[(dt * 16 + l15) * LP + ko];
        o[dt] = __builtin_amdgcn_mfma_f32_16x16x32_bf16(pf, vf, o[dt], 0, 0, 0);
      }
    }
  };

  // diagonal strided level: key j = i - 128s, block [k0s, k0s+64), k0s>=64
  auto strided_level = [&](int k0s) {
    __syncthreads();
    {
      const int r = tid >> 3, c = (tid & 7) * 8;
#pragma unroll
      for (int s2 = 0; s2 < 2; s2++) {
        const int rr = s2 * 32 + r;
        *(short8*)&Kls[rr * LP + c] = *(const short8*)&Kp[(size_t)(k0s + rr) * 64 + c];
        *(short8*)&Vtls[rr * LP + c] = *(const short8*)&Vp[(size_t)(k0s + rr) * 64 + c];
      }
    }
    __syncthreads();
    // dot: lane(quad,l15) -> row l15 of this wave, dim chunk quad*16
    const int rowl = wave * 16 + l15;
    const uint4v qv0 = *(const uint4v*)&Qls[rowl * LP + quad * 16];
    const uint4v qv1 = *(const uint4v*)&Qls[rowl * LP + quad * 16 + 8];
    const uint4v kv0 = *(const uint4v*)&Kls[rowl * LP + quad * 16];
    const uint4v kv1 = *(const uint4v*)&Kls[rowl * LP + quad * 16 + 8];
    float sd = 0.f;
#pragma unroll
    for (int m2 = 0; m2 < 4; m2++) {
      sd = dot2bf(qv0[m2], kv0[m2], sd);
      sd = dot2bf(qv1[m2], kv1[m2], sd);
    }
    sd += __shfl_xor(sd, 16);
    sd += __shfl_xor(sd, 32);
    const float sc = sd * scale;
#pragma unroll
    for (int r = 0; r < 4; r++) {
      const float sig = __shfl(sc, quad * 4 + r);  // score for row quad*4+r
      const float mnew = fmaxf(mrun[r], sig);
      const float al = __expf(mrun[r] - mnew);
      const float pr = __expf(sig - mnew);
      mrun[r] = mnew;
      lsum[r] = lsum[r] * al + pr;
      const int vr = wave * 16 + quad * 4 + r;
#pragma unroll
      for (int dt = 0; dt < 4; dt++)
        o[dt][r] = o[dt][r] * al + pr * b2f(Vtls[vr * LP + dt * 16 + l15]);
    }
  };

  if (qt < 6) {
    for (int kt = 0; kt <= qt; kt++) dense_tile(kt * 64, 3);
  } else {
    dense_tile(0, 3);                 // global + strided j<64
    dense_tile((qt - 4) * 64, 2);     // window edge + s=2 diag
    dense_tile((qt - 3) * 64, 0);
    dense_tile((qt - 2) * 64, 0);
    dense_tile((qt - 1) * 64, 0);
    dense_tile(qt * 64, 1);           // causal diag
    for (int k0s = q0 - 384; k0s >= 64; k0s -= 128) strided_level(k0s);
  }

#pragma unroll
  for (int dt = 0; dt < 4; dt++) {
#pragma unroll
    for (int r = 0; r < 4; r++) {
      const int t = q0 + wave * 16 + quad * 4 + r;
      const int c = h * 64 + dt * 16 + l15;
      Y[(size_t)(b * 4096 + t) * 1024 + c] = f2b(o[dt][r] / lsum[r]);
    }
  }
}

// ---- launch -----------------------------------------------------------------
static const void* by_size(void* const* d_in, const int* in_sizes, int n_in,
                           int want, int fallback_idx) {
  for (int i = 0; i < n_in; i++)
    if (in_sizes[i] == want) return d_in[i];
  return d_in[fallback_idx];
}

extern "C" void kernel_launch(void* const* d_in, const int* in_sizes, int n_in,
                              void* d_out, int out_size, void* d_ws,
                              size_t ws_size, hipStream_t stream) {
  const float* x      = (const float*)by_size(d_in, in_sizes, n_in, 8388608, 0);
  const float* w_qkv  = (const float*)by_size(d_in, in_sizes, n_in, 3145728, 1);
  const float* b_qkv  = (const float*)by_size(d_in, in_sizes, n_in, 3072, 2);
  const float* w_proj = (const float*)by_size(d_in, in_sizes, n_in, 1048576, 3);
  const float* b_proj = (const float*)by_size(d_in, in_sizes, n_in, 1024, 4);
  float* out = (float*)d_out;                     // [2,4096,1024] f32
  char* ws = (char*)d_ws;
  ushort_t* wqkvT  = (ushort_t*)(ws);             //  6.3 MB bf16 [3072,1024]
  ushort_t* wprojT = (ushort_t*)(ws + 6291456);   //  2.1 MB bf16 [1024,1024]
  ushort_t* qb     = (ushort_t*)(ws + 8388608);   // 16.8 MB bf16 [B,H,T,D]
  ushort_t* kb     = (ushort_t*)(ws + 25165824);
  ushort_t* vb     = (ushort_t*)(ws + 41943040);
  ushort_t* yb     = (ushort_t*)(ws + 58720256);  // 16.8 MB bf16 [8192,1024]
  ushort_t* xb     = yb;  // x-bf16 aliases yb: dead before attention writes yb

  if (ws_size < 75497472) return;  // proven satisfied

  f32_to_b16<<<4096, 256, 0, stream>>>(x, xb);
  transpose_f2b<<<dim3(16, 48), 256, 0, stream>>>(w_qkv, wqkvT, 1024, 3072);
  transpose_f2b<<<dim3(16, 16), 256, 0, stream>>>(w_proj, wprojT, 1024, 1024);
  gemm_bt<0><<<dim3(24, 64), 256, 0, stream>>>(
      xb, wqkvT, b_qkv, qb, kb, vb, nullptr, 8192, 3072, 1024);
  sparse_attn<<<dim3(64, 16, 2), 256, 0, stream>>>(qb, kb, vb, yb);
  gemm_bt<1><<<dim3(8, 64), 256, 0, stream>>>(
      yb, wprojT, b_proj, nullptr, nullptr, nullptr, out, 8192, 1024, 1024);
}